// Round 11
// baseline (296.373 us; speedup 1.0000x reference)
//
#include <hip/hip_runtime.h>
#include <hip/hip_bf16.h>

typedef __bf16 bf16_t;
typedef __bf16 bf16x4 __attribute__((ext_vector_type(4)));
typedef __bf16 bf16x8 __attribute__((ext_vector_type(8)));
typedef float f32x4 __attribute__((ext_vector_type(4)));
typedef float f32x8 __attribute__((ext_vector_type(8)));

#define MFMA16(a, b, c) __builtin_amdgcn_mfma_f32_16x16x32_bf16((a), (b), (c), 0, 0, 0)

#if __has_builtin(__builtin_amdgcn_exp2f)
#define EXP2(x) __builtin_amdgcn_exp2f(x)
#else
#define EXP2(x) exp2f(x)
#endif

// Address-space casts for global_load_lds (HBM -> LDS direct, width 16).
#define AS1(p) ((const __attribute__((address_space(1))) void*)(p))
#define AS3(p) ((__attribute__((address_space(3))) void*)(p))

// Problem constants: B=2, C=512, H=W=64, N=4096, heads=8, dh=64
#define NPIX 4096
#define CDIM 512
// q pre-scale: dh^-0.5 * log2(e) so softmax is a bare exp2
#define QSCALE 0.1803368801111744f

// attn LDS row stride: 72 elems (144B).  R4: stride must be 16B-multiple
// (b128 alignment); residual 8-way fragment-read conflict is the b128
// bandwidth floor (64 lanes x 16B = 1024B / 128B-per-cycle = 8 cy min).
#define KSTR 72
#define KTILE (64 * KSTR)  // one double-buffer half, elems

// dwconv LDS row stride (R10): 200 elems = 400B == 0 mod 16 -> rows are
// b128-aligned so the compute phase reads bf16x8 vectors.
#define DWSTR 200

// Wave-uniform dtype self-detect (see earlier rounds).
__device__ __forceinline__ bool detect_f32(const void* p) {
  const unsigned short* u = (const unsigned short*)p;
  int lane = threadIdx.x & 63;
  int f = 0;
#pragma unroll
  for (int j = 0; j < 4; ++j) {
    int e = (u[lane * 4 + j] >> 7) & 0xFF;
    f |= (e >= 138) ? 1 : 0;
  }
  return __ballot(f) != 0ull;
}

// ---------------------------------------------------------------------------
// Kernel 1 (R9 fused + R10 vectorized): blocks < 1024 do the depthwise 3x3
// conv (x (B,C,64,64) -> y_t (B,N,C)); blocks >= 1024 convert qkvw/projw
// f32->bf16 (R7 win).  R11: the last w2b block also zeroes the 256 split-K
// combine flags (stream-ordered before attn; re-zeroed every launch so the
// scheme is robust to workspace poisoning and graph replay).
// ---------------------------------------------------------------------------
__global__ __launch_bounds__(256) void dwconv_kernel(
    const void* __restrict__ x_, const void* __restrict__ dww_,
    bf16_t* __restrict__ yt, const void* __restrict__ qkvw,
    const void* __restrict__ projw, bf16_t* __restrict__ wq,
    bf16_t* __restrict__ wp, int* __restrict__ flags) {
  __shared__ bf16_t xs[64 * DWSTR];  // [c][r*64 + w], stride 200
  __shared__ float wsh[64 * 9];
  int bidx = blockIdx.x;
  int tid = threadIdx.x;

  if (bidx >= 1024) {  // ---- w2b branch: weight f32->bf16 ----
    int bid = bidx - 1024;
    const void* src;
    bf16_t* dst;
    int off;
    if (bid < 384) {
      src = qkvw; dst = wq; off = bid * 2048;
    } else {
      src = projw; dst = wp; off = (bid - 384) * 2048;
    }
    const bool wf32 = detect_f32(src);
    int i = off + tid * 8;
    if (wf32) {
      const float* p = (const float*)src + i;
      float4 t0 = *(const float4*)p;
      float4 t1 = *(const float4*)(p + 4);
      bf16x8 v;
      v[0] = (bf16_t)t0.x; v[1] = (bf16_t)t0.y;
      v[2] = (bf16_t)t0.z; v[3] = (bf16_t)t0.w;
      v[4] = (bf16_t)t1.x; v[5] = (bf16_t)t1.y;
      v[6] = (bf16_t)t1.z; v[7] = (bf16_t)t1.w;
      *(bf16x8*)&dst[i] = v;
    } else {
      *(bf16x8*)&dst[i] = *(const bf16x8*)((const bf16_t*)src + i);
    }
    if (bid == 511) flags[tid] = 0;  // 256 threads x 1 flag each
    return;
  }

  const bool f32m = detect_f32(x_);
  int c0 = (bidx & 7) << 6;
  int h = (bidx >> 3) & 63;
  int b = bidx >> 9;

  for (int i = tid; i < 576; i += 256)
    wsh[i] = f32m ? ((const float*)dww_)[c0 * 9 + i]
                  : (float)((const bf16_t*)dww_)[c0 * 9 + i];

  const size_t xoff = ((size_t)b * CDIM + c0) * NPIX;
#pragma unroll
  for (int r = 0; r < 3; ++r) {
    int hh = h + r - 1;
    bool ok = (unsigned)hh < 64u;
#pragma unroll
    for (int it = 0; it < 2; ++it) {
      int idx2 = tid + it * 256;
      int c = idx2 >> 3, ch = idx2 & 7;
      bf16x8 v = {};
      if (ok) {
        size_t gi = xoff + (size_t)c * NPIX + (size_t)hh * 64 + ch * 8;
        if (f32m) {
          const float* p = (const float*)x_ + gi;
          float4 t0 = *(const float4*)p;
          float4 t1 = *(const float4*)(p + 4);
          v[0] = (bf16_t)t0.x; v[1] = (bf16_t)t0.y;
          v[2] = (bf16_t)t0.z; v[3] = (bf16_t)t0.w;
          v[4] = (bf16_t)t1.x; v[5] = (bf16_t)t1.y;
          v[6] = (bf16_t)t1.z; v[7] = (bf16_t)t1.w;
        } else {
          v = *(const bf16x8*)((const bf16_t*)x_ + gi);
        }
      }
      *(bf16x8*)&xs[c * DWSTR + r * 64 + ch * 8] = v;  // 16B-aligned
    }
  }
  __syncthreads();

  int c = tid & 63;
  int wb = tid >> 6;
  int w0 = wb * 16;
  float wreg[9];
#pragma unroll
  for (int j = 0; j < 9; ++j) wreg[j] = wsh[c * 9 + j];
  const bf16_t* xrow = &xs[c * DWSTR];

  // register window: xw[r][k] = x[row r][w0 + k - 1]
  float xw[3][18];
#pragma unroll
  for (int r = 0; r < 3; ++r) {
    bf16x8 v0 = *(const bf16x8*)&xrow[r * 64 + w0];
    bf16x8 v1 = *(const bf16x8*)&xrow[r * 64 + w0 + 8];
    xw[r][0] = (wb > 0) ? (float)xrow[r * 64 + w0 - 1] : 0.f;
    xw[r][17] = (wb < 3) ? (float)xrow[r * 64 + w0 + 16] : 0.f;
#pragma unroll
    for (int i = 0; i < 8; ++i) {
      xw[r][1 + i] = (float)v0[i];
      xw[r][9 + i] = (float)v1[i];
    }
  }

  bf16_t* ybase = yt + ((size_t)b * NPIX + h * 64) * CDIM + c0 + c;
#pragma unroll
  for (int j = 0; j < 16; ++j) {
    float acc = 0.f;
#pragma unroll
    for (int r = 0; r < 3; ++r)
      acc += xw[r][j] * wreg[3 * r] + xw[r][j + 1] * wreg[3 * r + 1] +
             xw[r][j + 2] * wreg[3 * r + 2];
    ybase[(size_t)(w0 + j) * CDIM] = (bf16_t)acc;
  }
}

// ---------------------------------------------------------------------------
// GEMM (m97 recipe, R7-exact).  D[m][n] = sum_k A[m][k]*Bt[n][k].
// 128x128 tile, BK=32, unpadded [128][32] LDS tiles via global_load_lds
// width=16, single-buffered 2-barrier loop.  Grid: x=m-tile (fastest),
// y=n-tile, z=batch.  aconv=1: A_ pre-converted bf16 -> glds path.
// mode 0: -> q (scaled QSCALE), k, vT.  mode 1: -> proj out + bias.
// mode >= 2: B from split-K partials (fallback only).
// ---------------------------------------------------------------------------
__global__ __launch_bounds__(256) void gemm_kernel(
    const void* __restrict__ A_, const bf16_t* __restrict__ Bt,
    void* __restrict__ o0, bf16_t* __restrict__ o1, bf16_t* __restrict__ o2,
    const void* __restrict__ bias_, int mode, size_t pstride,
    const float* __restrict__ lsb, int aconv) {
  const int K = 512;
  __shared__ bf16_t as[128 * 32];
  __shared__ bf16_t bs[128 * 32];
  const bool f32m = detect_f32(bias_ ? bias_ : A_);
  int z = blockIdx.z;
  const bf16_t* Bz = Bt + (size_t)z * NPIX * K;
  int m0 = blockIdx.x * 128;
  int n0 = blockIdx.y * 128;
  int tid = threadIdx.x;
  int lane = tid & 63;
  int wv = tid >> 6;
  int wm = wv >> 1, wn = wv & 1;
  int col = lane & 15, quad = lane >> 4;

  f32x4 acc[4][4] = {};
  for (int ko = 0; ko < K; ko += 32) {
    // ---- stage A tile ----
    if (aconv || !f32m) {
#pragma unroll
      for (int j = 0; j < 2; ++j) {
        int i = tid + j * 256;
        int row = i >> 2, kc = (i & 3) << 3;
        __builtin_amdgcn_global_load_lds(
            AS1(&((const bf16_t*)A_)[(size_t)(m0 + row) * K + ko + kc]),
            AS3(&as[(wv * 64 + j * 256) * 8]), 16, 0, 0);
      }
    } else {
#pragma unroll
      for (int j = 0; j < 2; ++j) {
        int i = tid + j * 256;
        int row = i >> 2, kc = (i & 3) << 3;
        const float* p = &((const float*)A_)[(size_t)(m0 + row) * K + ko + kc];
        float4 t0 = *(const float4*)p;
        float4 t1 = *(const float4*)(p + 4);
        bf16x8 av;
        av[0] = (bf16_t)t0.x; av[1] = (bf16_t)t0.y;
        av[2] = (bf16_t)t0.z; av[3] = (bf16_t)t0.w;
        av[4] = (bf16_t)t1.x; av[5] = (bf16_t)t1.y;
        av[6] = (bf16_t)t1.z; av[7] = (bf16_t)t1.w;
        *(bf16x8*)&as[row * 32 + kc] = av;
      }
    }
    // ---- stage B tile ----
    if (mode < 2) {
#pragma unroll
      for (int j = 0; j < 2; ++j) {
        int i = tid + j * 256;
        int row = i >> 2, kc = (i & 3) << 3;
        __builtin_amdgcn_global_load_lds(
            AS1(&Bz[(size_t)(n0 + row) * K + ko + kc]),
            AS3(&bs[(wv * 64 + j * 256) * 8]), 16, 0, 0);
      }
    } else {
#pragma unroll
      for (int j = 0; j < 2; ++j) {
        int i = tid + j * 256;
        int row = i >> 2, kc = (i & 3) << 3;
        int hz = ko >> 6;  // head (BK=32 chunk never straddles a head)
        size_t qi = (size_t)(z * 8 + hz) * NPIX + n0 + row;
        float lacc = 0.f;
        for (int s = 0; s < mode; ++s)
          lacc += lsb[qi + (size_t)s * 16 * NPIX];
        float invl = 1.f / lacc;
        int d = (ko & 63) + kc;
        f32x8 f = {};
        for (int s = 0; s < mode; ++s) {
          bf16x8 p = *(const bf16x8*)&Bt[(size_t)s * pstride + qi * 64 + d];
#pragma unroll
          for (int e = 0; e < 8; ++e) f[e] += (float)p[e];
        }
#pragma unroll
        for (int e = 0; e < 8; ++e) f[e] *= invl;
        *(bf16x8*)&bs[row * 32 + kc] = __builtin_convertvector(f, bf16x8);
      }
    }
    __syncthreads();  // drains vmcnt (glds) + lgkmcnt (ds writes)

    bf16x8 af[4], bfr[4];
#pragma unroll
    for (int f = 0; f < 4; ++f) {
      af[f] = *(const bf16x8*)&as[(wm * 64 + f * 16 + col) * 32 + quad * 8];
      bfr[f] = *(const bf16x8*)&bs[(wn * 64 + f * 16 + col) * 32 + quad * 8];
    }
#pragma unroll
    for (int fm = 0; fm < 4; ++fm)
#pragma unroll
      for (int fn = 0; fn < 4; ++fn)
        acc[fm][fn] = MFMA16(af[fm], bfr[fn], acc[fm][fn]);
    __syncthreads();
  }

  if (mode == 0) {
    int t = m0 >> 9;  // 0=q 1=k 2=v
    float scale = (t == 0) ? QSCALE : 1.0f;
    bf16_t* q0 = (bf16_t*)o0;
#pragma unroll
    for (int fm = 0; fm < 4; ++fm) {
      int mloc = m0 + wm * 64 + fm * 16 + quad * 4;  // +r gives m
      int hh = (mloc & 511) >> 6;
      int d = mloc & 63;
#pragma unroll
      for (int fn = 0; fn < 4; ++fn) {
        int n = n0 + wn * 64 + fn * 16 + col;
        if (t < 2) {
          bf16_t* dst = ((t == 0) ? q0 : o1) +
                        ((size_t)z * 8 + hh) * ((size_t)NPIX * 64) +
                        (size_t)n * 64 + d;
          union {
            ushort4 u;
            bf16_t hv[4];
          } pk;
#pragma unroll
          for (int r = 0; r < 4; ++r) pk.hv[r] = (bf16_t)(acc[fm][fn][r] * scale);
          *(ushort4*)dst = pk.u;
        } else {
          // plain coalesced V^T store (consecutive col lanes -> consecutive n)
          bf16_t* vb = o2 + ((size_t)z * 8 + hh) * ((size_t)NPIX * 64);
#pragma unroll
          for (int r = 0; r < 4; ++r)
            vb[(size_t)(d + r) * NPIX + n] = (bf16_t)acc[fm][fn][r];
        }
      }
    }
  } else {
#pragma unroll
    for (int fm = 0; fm < 4; ++fm) {
      int mloc = m0 + wm * 64 + fm * 16 + quad * 4;
#pragma unroll
      for (int r = 0; r < 4; ++r) {
        float bv = f32m ? ((const float*)bias_)[mloc + r]
                        : (float)((const bf16_t*)bias_)[mloc + r];
#pragma unroll
        for (int fn = 0; fn < 4; ++fn) {
          int n = n0 + wn * 64 + fn * 16 + col;
          size_t oi = (size_t)z * CDIM * NPIX + (size_t)(mloc + r) * NPIX + n;
          float val = acc[fm][fn][r] + bv;
          if (f32m)
            ((float*)o0)[oi] = val;
          else
            ((bf16_t*)o0)[oi] = (bf16_t)val;
        }
      }
    }
  }
}

// ---------------------------------------------------------------------------
// Kernel 2.5 (R6; fallback only since R11): split-K combine.
// O = (O1 + O2) / (ls1 + ls2) in gemm-B layout.
// ---------------------------------------------------------------------------
__global__ __launch_bounds__(256) void combine_kernel(
    const bf16_t* __restrict__ O1, const bf16_t* __restrict__ O2,
    const float* __restrict__ ls, bf16_t* __restrict__ out) {
  int tid = threadIdx.x;
  int hd = tid & 63;
  int dn = tid >> 6;  // 0..3
  int h = hd >> 3;
  int dc = (hd & 7) << 3;
  int n = ((blockIdx.x & 1023) << 2) + dn;
  int z = blockIdx.x >> 10;
  size_t qi = (size_t)(z * 8 + h) * NPIX + n;
  float invl = 1.f / (ls[qi] + ls[qi + 16 * (size_t)NPIX]);
  bf16x8 p1 = *(const bf16x8*)&O1[qi * 64 + dc];
  bf16x8 p2 = *(const bf16x8*)&O2[qi * 64 + dc];
  f32x8 f;
#pragma unroll
  for (int e = 0; e < 8; ++e) f[e] = ((float)p1[e] + (float)p2[e]) * invl;
  *(bf16x8*)&out[((size_t)z * NPIX + n) * CDIM + h * 64 + dc] =
      __builtin_convertvector(f, bf16x8);
}

// ---------------------------------------------------------------------------
// Kernel 3: flash attention (transposed-S, no-max softmax), 64 q-rows/wave —
// main loop is the EXACT R0 configuration (75.6-76.6us; 898 TF = 2-barrier
// plain-HIP structural ceiling).  Locked: MODE>=2 split 2-way / grid 512 /
// (256,2); no setprio (R3: -13%); stride 72 (R4: b128 alignment).
// R11 MODE=3: last-block-combines — both blocks of a (bh,qt) pair write
// their partial + lsum as in MODE=2, then threadfence/syncthreads/atomicAdd
// (threadFenceReduction pattern, G12/G16); the SECOND finisher re-reads only
// the partner's partial (own half still in registers), normalizes by
// (ls1+ls2), and writes the final combined O directly in gemm-B layout.
// Replaces the separate combine kernel: -17MB traffic, -1 launch, and the
// combine overlaps with still-running attn blocks.  No spinning.
// ---------------------------------------------------------------------------
template <int MODE>
__global__ __launch_bounds__(256, 2) void attn_kernel(
    const bf16_t* __restrict__ q, const bf16_t* __restrict__ k,
    const bf16_t* __restrict__ vt, bf16_t* __restrict__ po,
    size_t posz, float* __restrict__ lsum, bf16_t* __restrict__ oc,
    int* __restrict__ flags) {
  __shared__ bf16_t ks[2 * KTILE];
  __shared__ bf16_t vs[2 * KTILE];  // V^T tile: [d][k-local, slot-permuted]
  __shared__ int shflag;
  int qt = blockIdx.x & 15;
  int bh = (blockIdx.x >> 4) & 15;
  int kh = (MODE >= 2) ? (blockIdx.x >> 8) : 0;
  const int kspan = (MODE >= 2) ? 32 : 64;  // MODE 2/3 are 2-way splits
  int kstart = kh * kspan;
  int kend = kstart + kspan;
  int tid = threadIdx.x;
  int lane = tid & 63, wv = tid >> 6;
  int col = lane & 15, quad = lane >> 4;
  const bf16_t* qb = q + (size_t)bh * NPIX * 64;
  const bf16_t* kb = k + (size_t)bh * NPIX * 64;
  const bf16_t* vb = vt + (size_t)bh * NPIX * 64;

  bf16x8 qfrag[4][2];
  int qrow0 = qt * 256 + wv * 64;
#pragma unroll
  for (int sub = 0; sub < 4; ++sub)
#pragma unroll
    for (int kk = 0; kk < 2; ++kk)
      qfrag[sub][kk] = *(const bf16x8*)&qb[(size_t)(qrow0 + sub * 16 + col) * 64 +
                                           kk * 32 + quad * 8];

  int trow = tid >> 2, t4 = tid & 3;
  bf16x8 kA0, kA1, vA0, vA1, kB0, kB1, vB0, vB1;
  auto loadKV = [&](int kc, bf16x8& k0, bf16x8& k1, bf16x8& v0, bf16x8& v1) {
    const bf16_t* kgr = &kb[(size_t)(kc * 64 + trow) * 64 + t4 * 16];
    const bf16_t* vgr = &vb[(size_t)trow * NPIX + kc * 64 + t4 * 16];
    k0 = *(const bf16x8*)kgr;
    k1 = *(const bf16x8*)(kgr + 8);
    v0 = *(const bf16x8*)vgr;
    v1 = *(const bf16x8*)(vgr + 8);
  };
  loadKV(kstart, kA0, kA1, vA0, vA1);
  loadKV(kstart + 1, kB0, kB1, vB0, vB1);

  int vbase = trow * KSTR + (t4 >> 1) * 32 + (t4 & 1) * 4;

  f32x4 oacc[4][4] = {};
  float lsv[4] = {0.f, 0.f, 0.f, 0.f};

  for (int kc = kstart; kc < kend; ++kc) {
    bf16_t* ksb = &ks[(kc & 1) * KTILE];
    bf16_t* vsb = &vs[(kc & 1) * KTILE];
    *(bf16x8*)&ksb[trow * KSTR + t4 * 16] = kA0;
    *(bf16x8*)&ksb[trow * KSTR + t4 * 16 + 8] = kA1;
    {
      union { bf16x8 v; bf16x4 h[2]; } u0, u1;
      u0.v = vA0; u1.v = vA1;
      *(bf16x4*)&vsb[vbase] = u0.h[0];
      *(bf16x4*)&vsb[vbase + 8] = u0.h[1];
      *(bf16x4*)&vsb[vbase + 16] = u1.h[0];
      *(bf16x4*)&vsb[vbase + 24] = u1.h[1];
    }
    __syncthreads();

    kA0 = kB0; kA1 = kB1; vA0 = vB0; vA1 = vB1;
    {
      int kcn = kc + 2;
      if (kcn >= kend) kcn = kstart;  // harmless reload
      loadKV(kcn, kB0, kB1, vB0, vB1);
    }

    bf16x8 kf[4][2];
#pragma unroll
    for (int nt = 0; nt < 4; ++nt)
#pragma unroll
      for (int kk = 0; kk < 2; ++kk)
        kf[nt][kk] =
            *(const bf16x8*)&ksb[(nt * 16 + col) * KSTR + kk * 32 + quad * 8];
    bf16x8 vf[4][2];
#pragma unroll
    for (int dt = 0; dt < 4; ++dt)
#pragma unroll
      for (int t = 0; t < 2; ++t)
        vf[dt][t] =
            *(const bf16x8*)&vsb[(dt * 16 + col) * KSTR + t * 32 + quad * 8];

#pragma unroll
    for (int sub = 0; sub < 4; ++sub) {
      f32x4 sv[4];
#pragma unroll
      for (int nt = 0; nt < 4; ++nt) {
        f32x4 s = {};
        s = MFMA16(kf[nt][0], qfrag[sub][0], s);
        s = MFMA16(kf[nt][1], qfrag[sub][1], s);
        sv[nt] = s;
      }
      bf16x8 pb[2];
      float ls = 0.f;
#pragma unroll
      for (int t = 0; t < 2; ++t) {
        f32x8 pe;
#pragma unroll
        for (int half = 0; half < 2; ++half)
#pragma unroll
          for (int r = 0; r < 4; ++r)
            pe[half * 4 + r] = EXP2(sv[2 * t + half][r]);
        float s0 = pe[0] + pe[1], s1 = pe[2] + pe[3];
        float s2 = pe[4] + pe[5], s3 = pe[6] + pe[7];
        ls += (s0 + s1) + (s2 + s3);
        pb[t] = __builtin_convertvector(pe, bf16x8);
      }
      lsv[sub] += ls;
#pragma unroll
      for (int dt = 0; dt < 4; ++dt) {
        oacc[sub][dt] = MFMA16(vf[dt][0], pb[0], oacc[sub][dt]);
        oacc[sub][dt] = MFMA16(vf[dt][1], pb[1], oacc[sub][dt]);
      }
    }
  }

#pragma unroll
  for (int sub = 0; sub < 4; ++sub) {
    lsv[sub] += __shfl_xor(lsv[sub], 16);
    lsv[sub] += __shfl_xor(lsv[sub], 32);
  }

  if (MODE == 0) {
    int b = bh >> 3, hh = bh & 7;
#pragma unroll
    for (int sub = 0; sub < 4; ++sub) {
      float inv = 1.f / lsv[sub];
      int qrow = qrow0 + sub * 16 + col;
      bf16_t* ob = po + ((size_t)b * NPIX + qrow) * CDIM + hh * 64 + quad * 4;
#pragma unroll
      for (int dt = 0; dt < 4; ++dt) {
        union {
          ushort4 u;
          bf16_t hv[4];
        } pk;
#pragma unroll
        for (int r = 0; r < 4; ++r)
          pk.hv[r] = (bf16_t)(oacc[sub][dt][r] * inv);
        *(ushort4*)(ob + dt * 16) = pk.u;
      }
    }
  } else {
    // ---- write own partial + lsum (MODE 2 and 3) ----
    bf16_t* pbase = po + (size_t)kh * posz;
#pragma unroll
    for (int sub = 0; sub < 4; ++sub) {
      int qrow = qrow0 + sub * 16 + col;
      bf16_t* op = pbase + ((size_t)bh * NPIX + qrow) * 64 + quad * 4;
#pragma unroll
      for (int dt = 0; dt < 4; ++dt) {
        union {
          ushort4 u;
          bf16_t hv[4];
        } pk;
#pragma unroll
        for (int r = 0; r < 4; ++r) pk.hv[r] = (bf16_t)oacc[sub][dt][r];
        *(ushort4*)(op + dt * 16) = pk.u;
      }
    }
    if (quad == 0) {
      float* lbase = lsum + (size_t)(kh * 16 + bh) * NPIX;
#pragma unroll
      for (int sub = 0; sub < 4; ++sub)
        lbase[qrow0 + sub * 16 + col] = lsv[sub];
    }

    if (MODE == 3) {
      // ---- last-block-combines (threadFenceReduction pattern) ----
      __threadfence();
      __syncthreads();
      if (tid == 0) shflag = atomicAdd(&flags[blockIdx.x & 255], 1);
      __syncthreads();
      if (shflag == 1) {
        __threadfence();  // acquire: invalidate caches before partner reads
        const bf16_t* qb2 =
            po + (size_t)(1 - kh) * posz + (size_t)bh * NPIX * 64;
        const float* plb = lsum + (size_t)((1 - kh) * 16 + bh) * NPIX;
        int z2 = bh >> 3, h2 = bh & 7;
#pragma unroll
        for (int sub = 0; sub < 4; ++sub) {
          int qrow = qrow0 + sub * 16 + col;
          float inv = 1.f / (lsv[sub] + plb[qrow]);
          const bf16_t* pp = qb2 + (size_t)qrow * 64 + quad * 4;
          bf16_t* ob =
              oc + ((size_t)z2 * NPIX + qrow) * CDIM + h2 * 64 + quad * 4;
#pragma unroll
          for (int dt = 0; dt < 4; ++dt) {
            union {
              ushort4 u;
              bf16_t hv[4];
            } pu, pk;
            pu.u = *(const ushort4*)(pp + dt * 16);
#pragma unroll
            for (int r = 0; r < 4; ++r)
              pk.hv[r] =
                  (bf16_t)((oacc[sub][dt][r] + (float)pu.hv[r]) * inv);
            *(ushort4*)(ob + dt * 16) = pk.u;
          }
        }
      }
    }
  }
}

// ---------------------------------------------------------------------------
extern "C" void kernel_launch(void* const* d_in, const int* in_sizes, int n_in,
                              void* d_out, int out_size, void* d_ws,
                              size_t ws_size, hipStream_t stream) {
  const void* x = d_in[0];
  const void* dww = d_in[1];
  const void* qkvw = d_in[2];
  const void* projw = d_in[3];
  const void* projb = d_in[4];

  bf16_t* ws = (bf16_t*)d_ws;
  const size_t SZ = (size_t)2 * NPIX * CDIM;  // 4,194,304 elems per buffer
  bf16_t* yt = ws;           // y_t (B,N,C); dead after gemm1
  bf16_t* qa = ws + SZ;      // q (b,h,n,d), pre-scaled by QSCALE
  bf16_t* ka = ws + 2 * SZ;  // k (b,h,n,d)
  bf16_t* va = ws + 3 * SZ;  // vT (b,h,d,n), plain layout

  // Layout: partial kh=0 overlays yt, partial kh=1 at ws+4SZ (stride 4SZ),
  // lsum (2*16*NPIX f32 = 262144 bf16-slots) at ws+5SZ, converted weights
  // wq/wp after lsum, combine flags (256 ints) after wp, combined O at
  // ws+6SZ.
  const size_t needC = 7 * SZ * sizeof(bf16_t);
  const size_t need2 =
      5 * SZ * sizeof(bf16_t) + 2 * 16 * (size_t)NPIX * sizeof(float);

  if (ws_size >= needC) {
    bf16_t* O1 = yt;  // partial kh=0 overlays yt
    float* ls2 = (float*)(ws + 5 * SZ);
    bf16_t* wq = ws + 5 * SZ + 262144;  // 786432 elems
    bf16_t* wp = wq + 786432;           // 262144 elems
    int* flags = (int*)(wp + 262144);   // 256 ints
    bf16_t* oc = ws + 6 * SZ;  // combined, gemm-B layout (z, n, 512)
    // fused: blocks 0-1023 dwconv, 1024-1535 weight convert (+flag zero)
    dwconv_kernel<<<1536, 256, 0, stream>>>(x, dww, yt, qkvw, projw, wq, wp,
                                            flags);
    // m-tile fastest: consecutive blocks share the B-tile (L2 reuse)
    gemm_kernel<<<dim3(12, 32, 2), 256, 0, stream>>>(
        wq, yt, qa, ka, va, nullptr, 0, 0, nullptr, 1);
    attn_kernel<3><<<512, 256, 0, stream>>>(qa, ka, va, O1, 4 * SZ, ls2, oc,
                                            flags);
    gemm_kernel<<<dim3(4, 32, 2), 256, 0, stream>>>(
        wp, oc, d_out, nullptr, nullptr, projb, 1, 0, nullptr, 1);
  } else if (ws_size >= need2) {
    bf16_t* O1 = yt;  // partial s=0 overlays yt
    float* ls2 = (float*)(ws + 5 * SZ);
    dwconv_kernel<<<1024, 256, 0, stream>>>(x, dww, yt, nullptr, nullptr,
                                            nullptr, nullptr, nullptr);
    gemm_kernel<<<dim3(12, 32, 2), 256, 0, stream>>>(
        qkvw, yt, qa, ka, va, nullptr, 0, 0, nullptr, 0);
    attn_kernel<2><<<512, 256, 0, stream>>>(qa, ka, va, O1, 4 * SZ, ls2,
                                            nullptr, nullptr);
    gemm_kernel<<<dim3(4, 32, 2), 256, 0, stream>>>(
        projw, O1, d_out, nullptr, nullptr, projb, 2, 4 * SZ, ls2, 0);
  } else {
    dwconv_kernel<<<1024, 256, 0, stream>>>(x, dww, yt, nullptr, nullptr,
                                            nullptr, nullptr, nullptr);
    gemm_kernel<<<dim3(12, 32, 2), 256, 0, stream>>>(
        qkvw, yt, qa, ka, va, nullptr, 0, 0, nullptr, 0);
    attn_kernel<0><<<256, 256, 0, stream>>>(qa, ka, va, yt, 0, nullptr,
                                            nullptr, nullptr);
    gemm_kernel<<<dim3(4, 32, 2), 256, 0, stream>>>(
        projw, yt, d_out, nullptr, nullptr, projb, 1, 0, nullptr, 0);
  }
}

// Round 12
// 190.190 us; speedup vs baseline: 1.5583x; 1.5583x over previous
//
#include <hip/hip_runtime.h>
#include <hip/hip_bf16.h>

typedef __bf16 bf16_t;
typedef __bf16 bf16x4 __attribute__((ext_vector_type(4)));
typedef __bf16 bf16x8 __attribute__((ext_vector_type(8)));
typedef float f32x4 __attribute__((ext_vector_type(4)));
typedef float f32x8 __attribute__((ext_vector_type(8)));

#define MFMA16(a, b, c) __builtin_amdgcn_mfma_f32_16x16x32_bf16((a), (b), (c), 0, 0, 0)

#if __has_builtin(__builtin_amdgcn_exp2f)
#define EXP2(x) __builtin_amdgcn_exp2f(x)
#else
#define EXP2(x) exp2f(x)
#endif

// Address-space casts for global_load_lds (HBM -> LDS direct, width 16).
#define AS1(p) ((const __attribute__((address_space(1))) void*)(p))
#define AS3(p) ((__attribute__((address_space(3))) void*)(p))

// Problem constants: B=2, C=512, H=W=64, N=4096, heads=8, dh=64
#define NPIX 4096
#define CDIM 512
// q pre-scale: dh^-0.5 * log2(e) so softmax is a bare exp2
#define QSCALE 0.1803368801111744f

// attn LDS row stride: 72 elems (144B).  R4: stride must be 16B-multiple
// (b128 alignment); residual 8-way fragment-read conflict is the b128
// bandwidth floor (64 lanes x 16B = 1024B / 128B-per-cycle = 8 cy min).
#define KSTR 72
#define KTILE (64 * KSTR)  // one double-buffer half, elems

// Wave-uniform dtype self-detect (see earlier rounds).
__device__ __forceinline__ bool detect_f32(const void* p) {
  const unsigned short* u = (const unsigned short*)p;
  int lane = threadIdx.x & 63;
  int f = 0;
#pragma unroll
  for (int j = 0; j < 4; ++j) {
    int e = (u[lane * 4 + j] >> 7) & 0xFF;
    f |= (e >= 138) ? 1 : 0;
  }
  return __ballot(f) != 0ull;
}

// ---------------------------------------------------------------------------
// Kernel 1 (R9-exact): blocks < 1024 do the depthwise 3x3 conv
// (x (B,C,64,64) -> y_t (B,N,C); bf16x8 staging, LDS stride 194); blocks
// >= 1024 convert qkvw/projw f32->bf16 (R7 win: both GEMMs stage A via
// global_load_lds; m151 reg-staging ~26% slower).  Data-independent bodies;
// fusing removes one serialized launch (R9: -3.3us).
// R11 lesson (reverted): intra-kernel cross-block combine via device-scope
// fences trashed the per-XCD L2s (attn 76->190us) — keep separate kernels.
// ---------------------------------------------------------------------------
__global__ __launch_bounds__(256) void dwconv_kernel(
    const void* __restrict__ x_, const void* __restrict__ dww_,
    bf16_t* __restrict__ yt, const void* __restrict__ qkvw,
    const void* __restrict__ projw, bf16_t* __restrict__ wq,
    bf16_t* __restrict__ wp) {
  __shared__ bf16_t xs[64 * 194];  // [c][r*64 + w], stride 194
  __shared__ float wsh[64 * 9];
  int bidx = blockIdx.x;
  int tid = threadIdx.x;

  if (bidx >= 1024) {  // ---- w2b branch: weight f32->bf16 ----
    int bid = bidx - 1024;
    const void* src;
    bf16_t* dst;
    int off;
    if (bid < 384) {
      src = qkvw; dst = wq; off = bid * 2048;
    } else {
      src = projw; dst = wp; off = (bid - 384) * 2048;
    }
    const bool wf32 = detect_f32(src);
    int i = off + tid * 8;
    if (wf32) {
      const float* p = (const float*)src + i;
      float4 t0 = *(const float4*)p;
      float4 t1 = *(const float4*)(p + 4);
      bf16x8 v;
      v[0] = (bf16_t)t0.x; v[1] = (bf16_t)t0.y;
      v[2] = (bf16_t)t0.z; v[3] = (bf16_t)t0.w;
      v[4] = (bf16_t)t1.x; v[5] = (bf16_t)t1.y;
      v[6] = (bf16_t)t1.z; v[7] = (bf16_t)t1.w;
      *(bf16x8*)&dst[i] = v;
    } else {
      *(bf16x8*)&dst[i] = *(const bf16x8*)((const bf16_t*)src + i);
    }
    return;
  }

  const bool f32m = detect_f32(x_);
  int c0 = (bidx & 7) << 6;
  int h = (bidx >> 3) & 63;
  int b = bidx >> 9;

  for (int i = tid; i < 576; i += 256)
    wsh[i] = f32m ? ((const float*)dww_)[c0 * 9 + i]
                  : (float)((const bf16_t*)dww_)[c0 * 9 + i];

  const size_t xoff = ((size_t)b * CDIM + c0) * NPIX;
#pragma unroll
  for (int r = 0; r < 3; ++r) {
    int hh = h + r - 1;
    bool ok = (unsigned)hh < 64u;
#pragma unroll
    for (int it = 0; it < 2; ++it) {
      int idx2 = tid + it * 256;
      int c = idx2 >> 3, ch = idx2 & 7;
      bf16x8 v = {};
      if (ok) {
        size_t gi = xoff + (size_t)c * NPIX + (size_t)hh * 64 + ch * 8;
        if (f32m) {
          const float* p = (const float*)x_ + gi;
          float4 t0 = *(const float4*)p;
          float4 t1 = *(const float4*)(p + 4);
          v[0] = (bf16_t)t0.x; v[1] = (bf16_t)t0.y;
          v[2] = (bf16_t)t0.z; v[3] = (bf16_t)t0.w;
          v[4] = (bf16_t)t1.x; v[5] = (bf16_t)t1.y;
          v[6] = (bf16_t)t1.z; v[7] = (bf16_t)t1.w;
        } else {
          v = *(const bf16x8*)((const bf16_t*)x_ + gi);
        }
      }
      union { bf16x8 v8; unsigned u[4]; } uu;
      uu.v8 = v;
      unsigned* dst = (unsigned*)&xs[c * 194 + r * 64 + ch * 8];
      dst[0] = uu.u[0]; dst[1] = uu.u[1]; dst[2] = uu.u[2]; dst[3] = uu.u[3];
    }
  }
  __syncthreads();

  int c = tid & 63;
  int wb = tid >> 6;
  float wreg[9];
#pragma unroll
  for (int j = 0; j < 9; ++j) wreg[j] = wsh[c * 9 + j];
  const bf16_t* xrow = &xs[c * 194];
  bf16_t* ybase = yt + ((size_t)b * NPIX + h * 64) * CDIM + c0 + c;
#pragma unroll
  for (int jj = 0; jj < 16; ++jj) {
    int w = wb + 4 * jj;
    float acc = 0.f;
#pragma unroll
    for (int r = 0; r < 3; ++r) {
      float xm = (w > 0) ? (float)xrow[r * 64 + w - 1] : 0.f;
      float xc = (float)xrow[r * 64 + w];
      float xp = (w < 63) ? (float)xrow[r * 64 + w + 1] : 0.f;
      acc += xm * wreg[3 * r] + xc * wreg[3 * r + 1] + xp * wreg[3 * r + 2];
    }
    ybase[(size_t)w * CDIM] = (bf16_t)acc;
  }
}

// ---------------------------------------------------------------------------
// GEMM (m97 recipe, R7-exact loop), templated on BN (R12): D[m][n] =
// sum_k A[m][k]*Bt[n][k].  128xBN tile, BK=32, unpadded LDS tiles via
// global_load_lds width=16, single-buffered 2-barrier loop.
// BN=128: exact R7/R9 configuration (gemm1 + all fallbacks).
// BN=64 (gemm2): grid 4x64x2 = 512 blocks = 2 blocks/CU (was 256 = 1/CU,
// every barrier drain exposed with no co-resident block); per-wave acc
// halves to acc[4][2].  Wave layout: 2x2 waves, each 64m x (BN/2)n.
// aconv=1: A_ pre-converted bf16 -> glds path regardless of input dtype.
// mode 0: -> q (scaled QSCALE), k, vT.  mode 1: -> proj out + bias.
// mode >= 2: B from split-K partials (fallback only, BN=128).
// ---------------------------------------------------------------------------
template <int BN>
__global__ __launch_bounds__(256) void gemm_kernel(
    const void* __restrict__ A_, const bf16_t* __restrict__ Bt,
    void* __restrict__ o0, bf16_t* __restrict__ o1, bf16_t* __restrict__ o2,
    const void* __restrict__ bias_, int mode, size_t pstride,
    const float* __restrict__ lsb, int aconv) {
  const int K = 512;
  constexpr int NF = BN / 32;  // n-fragments per wave
  __shared__ bf16_t as[128 * 32];
  __shared__ bf16_t bs[BN * 32];
  const bool f32m = detect_f32(bias_ ? bias_ : A_);
  int z = blockIdx.z;
  const bf16_t* Bz = Bt + (size_t)z * NPIX * K;
  int m0 = blockIdx.x * 128;
  int n0 = blockIdx.y * BN;
  int tid = threadIdx.x;
  int lane = tid & 63;
  int wv = tid >> 6;
  int wm = wv >> 1, wn = wv & 1;
  int col = lane & 15, quad = lane >> 4;

  f32x4 acc[4][NF] = {};
  for (int ko = 0; ko < K; ko += 32) {
    // ---- stage A tile (128x32) ----
    if (aconv || !f32m) {
#pragma unroll
      for (int j = 0; j < 2; ++j) {
        int i = tid + j * 256;
        int row = i >> 2, kc = (i & 3) << 3;
        __builtin_amdgcn_global_load_lds(
            AS1(&((const bf16_t*)A_)[(size_t)(m0 + row) * K + ko + kc]),
            AS3(&as[(wv * 64 + j * 256) * 8]), 16, 0, 0);
      }
    } else {
#pragma unroll
      for (int j = 0; j < 2; ++j) {
        int i = tid + j * 256;
        int row = i >> 2, kc = (i & 3) << 3;
        const float* p = &((const float*)A_)[(size_t)(m0 + row) * K + ko + kc];
        float4 t0 = *(const float4*)p;
        float4 t1 = *(const float4*)(p + 4);
        bf16x8 av;
        av[0] = (bf16_t)t0.x; av[1] = (bf16_t)t0.y;
        av[2] = (bf16_t)t0.z; av[3] = (bf16_t)t0.w;
        av[4] = (bf16_t)t1.x; av[5] = (bf16_t)t1.y;
        av[6] = (bf16_t)t1.z; av[7] = (bf16_t)t1.w;
        *(bf16x8*)&as[row * 32 + kc] = av;
      }
    }
    // ---- stage B tile (BNx32) ----
    if (mode < 2) {
#pragma unroll
      for (int j = 0; j < BN / 64; ++j) {
        int i = tid + j * 256;
        int row = i >> 2, kc = (i & 3) << 3;
        __builtin_amdgcn_global_load_lds(
            AS1(&Bz[(size_t)(n0 + row) * K + ko + kc]),
            AS3(&bs[(wv * 64 + j * 256) * 8]), 16, 0, 0);
      }
    } else {
#pragma unroll
      for (int j = 0; j < BN / 64; ++j) {
        int i = tid + j * 256;
        int row = i >> 2, kc = (i & 3) << 3;
        int hz = ko >> 6;  // head (BK=32 chunk never straddles a head)
        size_t qi = (size_t)(z * 8 + hz) * NPIX + n0 + row;
        float lacc = 0.f;
        for (int s = 0; s < mode; ++s)
          lacc += lsb[qi + (size_t)s * 16 * NPIX];
        float invl = 1.f / lacc;
        int d = (ko & 63) + kc;
        f32x8 f = {};
        for (int s = 0; s < mode; ++s) {
          bf16x8 p = *(const bf16x8*)&Bt[(size_t)s * pstride + qi * 64 + d];
#pragma unroll
          for (int e = 0; e < 8; ++e) f[e] += (float)p[e];
        }
#pragma unroll
        for (int e = 0; e < 8; ++e) f[e] *= invl;
        *(bf16x8*)&bs[row * 32 + kc] = __builtin_convertvector(f, bf16x8);
      }
    }
    __syncthreads();  // drains vmcnt (glds) + lgkmcnt (ds writes)

    bf16x8 af[4], bfr[NF];
#pragma unroll
    for (int f = 0; f < 4; ++f)
      af[f] = *(const bf16x8*)&as[(wm * 64 + f * 16 + col) * 32 + quad * 8];
#pragma unroll
    for (int f = 0; f < NF; ++f)
      bfr[f] =
          *(const bf16x8*)&bs[(wn * (BN / 2) + f * 16 + col) * 32 + quad * 8];
#pragma unroll
    for (int fm = 0; fm < 4; ++fm)
#pragma unroll
      for (int fn = 0; fn < NF; ++fn)
        acc[fm][fn] = MFMA16(af[fm], bfr[fn], acc[fm][fn]);
    __syncthreads();
  }

  if (mode == 0) {
    int t = m0 >> 9;  // 0=q 1=k 2=v
    float scale = (t == 0) ? QSCALE : 1.0f;
    bf16_t* q0 = (bf16_t*)o0;
#pragma unroll
    for (int fm = 0; fm < 4; ++fm) {
      int mloc = m0 + wm * 64 + fm * 16 + quad * 4;  // +r gives m
      int hh = (mloc & 511) >> 6;
      int d = mloc & 63;
#pragma unroll
      for (int fn = 0; fn < NF; ++fn) {
        int n = n0 + wn * (BN / 2) + fn * 16 + col;
        if (t < 2) {
          bf16_t* dst = ((t == 0) ? q0 : o1) +
                        ((size_t)z * 8 + hh) * ((size_t)NPIX * 64) +
                        (size_t)n * 64 + d;
          union {
            ushort4 u;
            bf16_t hv[4];
          } pk;
#pragma unroll
          for (int r = 0; r < 4; ++r) pk.hv[r] = (bf16_t)(acc[fm][fn][r] * scale);
          *(ushort4*)dst = pk.u;
        } else {
          // plain coalesced V^T store (consecutive col lanes -> consecutive n)
          bf16_t* vb = o2 + ((size_t)z * 8 + hh) * ((size_t)NPIX * 64);
#pragma unroll
          for (int r = 0; r < 4; ++r)
            vb[(size_t)(d + r) * NPIX + n] = (bf16_t)acc[fm][fn][r];
        }
      }
    }
  } else {
#pragma unroll
    for (int fm = 0; fm < 4; ++fm) {
      int mloc = m0 + wm * 64 + fm * 16 + quad * 4;
#pragma unroll
      for (int r = 0; r < 4; ++r) {
        float bv = f32m ? ((const float*)bias_)[mloc + r]
                        : (float)((const bf16_t*)bias_)[mloc + r];
#pragma unroll
        for (int fn = 0; fn < NF; ++fn) {
          int n = n0 + wn * (BN / 2) + fn * 16 + col;
          size_t oi = (size_t)z * CDIM * NPIX + (size_t)(mloc + r) * NPIX + n;
          float val = acc[fm][fn][r] + bv;
          if (f32m)
            ((float*)o0)[oi] = val;
          else
            ((bf16_t*)o0)[oi] = (bf16_t)val;
        }
      }
    }
  }
}

// ---------------------------------------------------------------------------
// Kernel 2.5 (R6): split-K combine.  O = (O1 + O2) / (ls1 + ls2), written
// ONCE in gemm-B layout (z, n, c=h*64+d) so gemm2 runs mode 1 with the fast
// glds B-staging path.  Fully coalesced (1KB/wave stores).  R11 proved this
// separate kernel beats intra-attn fused combine (device fences trash L2).
// ---------------------------------------------------------------------------
__global__ __launch_bounds__(256) void combine_kernel(
    const bf16_t* __restrict__ O1, const bf16_t* __restrict__ O2,
    const float* __restrict__ ls, bf16_t* __restrict__ out) {
  int tid = threadIdx.x;
  int hd = tid & 63;
  int dn = tid >> 6;  // 0..3
  int h = hd >> 3;
  int dc = (hd & 7) << 3;
  int n = ((blockIdx.x & 1023) << 2) + dn;
  int z = blockIdx.x >> 10;
  size_t qi = (size_t)(z * 8 + h) * NPIX + n;
  float invl = 1.f / (ls[qi] + ls[qi + 16 * (size_t)NPIX]);
  bf16x8 p1 = *(const bf16x8*)&O1[qi * 64 + dc];
  bf16x8 p2 = *(const bf16x8*)&O2[qi * 64 + dc];
  f32x8 f;
#pragma unroll
  for (int e = 0; e < 8; ++e) f[e] = ((float)p1[e] + (float)p2[e]) * invl;
  *(bf16x8*)&out[((size_t)z * NPIX + n) * CDIM + h * 64 + dc] =
      __builtin_convertvector(f, bf16x8);
}

// ---------------------------------------------------------------------------
// Kernel 3: flash attention (transposed-S, no-max softmax), 64 q-rows/wave —
// EXACT R0 configuration (best measured: 75.6-76.6us; 898 TF = 2-barrier
// plain-HIP structural ceiling).  Locked by R1-R5/R11 evidence: MODE=2 /
// grid 512 / (256,2) (occupancy register-capped at 2 waves/SIMD); no
// setprio (R3: -13%); stride 72 (R4: b128 alignment); no intra-kernel
// combine (R11: device fences -> L2 trash, 76->190us).
// ---------------------------------------------------------------------------
template <int MODE>
__global__ __launch_bounds__(256, 2) void attn_kernel(
    const bf16_t* __restrict__ q, const bf16_t* __restrict__ k,
    const bf16_t* __restrict__ vt, bf16_t* __restrict__ po,
    size_t posz, float* __restrict__ lsum) {
  __shared__ bf16_t ks[2 * KTILE];
  __shared__ bf16_t vs[2 * KTILE];  // V^T tile: [d][k-local, slot-permuted]
  int qt = blockIdx.x & 15;
  int bh = (blockIdx.x >> 4) & 15;
  int kh = (MODE >= 2) ? (blockIdx.x >> 8) : 0;
  const int kspan = (MODE >= 2) ? (64 / MODE) : 64;
  int kstart = kh * kspan;
  int kend = kstart + kspan;
  int tid = threadIdx.x;
  int lane = tid & 63, wv = tid >> 6;
  int col = lane & 15, quad = lane >> 4;
  const bf16_t* qb = q + (size_t)bh * NPIX * 64;
  const bf16_t* kb = k + (size_t)bh * NPIX * 64;
  const bf16_t* vb = vt + (size_t)bh * NPIX * 64;

  bf16x8 qfrag[4][2];
  int qrow0 = qt * 256 + wv * 64;
#pragma unroll
  for (int sub = 0; sub < 4; ++sub)
#pragma unroll
    for (int kk = 0; kk < 2; ++kk)
      qfrag[sub][kk] = *(const bf16x8*)&qb[(size_t)(qrow0 + sub * 16 + col) * 64 +
                                           kk * 32 + quad * 8];

  int trow = tid >> 2, t4 = tid & 3;
  bf16x8 kA0, kA1, vA0, vA1, kB0, kB1, vB0, vB1;
  auto loadKV = [&](int kc, bf16x8& k0, bf16x8& k1, bf16x8& v0, bf16x8& v1) {
    const bf16_t* kgr = &kb[(size_t)(kc * 64 + trow) * 64 + t4 * 16];
    const bf16_t* vgr = &vb[(size_t)trow * NPIX + kc * 64 + t4 * 16];
    k0 = *(const bf16x8*)kgr;
    k1 = *(const bf16x8*)(kgr + 8);
    v0 = *(const bf16x8*)vgr;
    v1 = *(const bf16x8*)(vgr + 8);
  };
  loadKV(kstart, kA0, kA1, vA0, vA1);
  loadKV(kstart + 1, kB0, kB1, vB0, vB1);

  int vbase = trow * KSTR + (t4 >> 1) * 32 + (t4 & 1) * 4;

  f32x4 oacc[4][4] = {};
  float lsv[4] = {0.f, 0.f, 0.f, 0.f};

  for (int kc = kstart; kc < kend; ++kc) {
    bf16_t* ksb = &ks[(kc & 1) * KTILE];
    bf16_t* vsb = &vs[(kc & 1) * KTILE];
    *(bf16x8*)&ksb[trow * KSTR + t4 * 16] = kA0;
    *(bf16x8*)&ksb[trow * KSTR + t4 * 16 + 8] = kA1;
    {
      union { bf16x8 v; bf16x4 h[2]; } u0, u1;
      u0.v = vA0; u1.v = vA1;
      *(bf16x4*)&vsb[vbase] = u0.h[0];
      *(bf16x4*)&vsb[vbase + 8] = u0.h[1];
      *(bf16x4*)&vsb[vbase + 16] = u1.h[0];
      *(bf16x4*)&vsb[vbase + 24] = u1.h[1];
    }
    __syncthreads();

    kA0 = kB0; kA1 = kB1; vA0 = vB0; vA1 = vB1;
    {
      int kcn = kc + 2;
      if (kcn >= kend) kcn = kstart;  // harmless reload
      loadKV(kcn, kB0, kB1, vB0, vB1);
    }

    bf16x8 kf[4][2];
#pragma unroll
    for (int nt = 0; nt < 4; ++nt)
#pragma unroll
      for (int kk = 0; kk < 2; ++kk)
        kf[nt][kk] =
            *(const bf16x8*)&ksb[(nt * 16 + col) * KSTR + kk * 32 + quad * 8];
    bf16x8 vf[4][2];
#pragma unroll
    for (int dt = 0; dt < 4; ++dt)
#pragma unroll
      for (int t = 0; t < 2; ++t)
        vf[dt][t] =
            *(const bf16x8*)&vsb[(dt * 16 + col) * KSTR + t * 32 + quad * 8];

#pragma unroll
    for (int sub = 0; sub < 4; ++sub) {
      f32x4 sv[4];
#pragma unroll
      for (int nt = 0; nt < 4; ++nt) {
        f32x4 s = {};
        s = MFMA16(kf[nt][0], qfrag[sub][0], s);
        s = MFMA16(kf[nt][1], qfrag[sub][1], s);
        sv[nt] = s;
      }
      bf16x8 pb[2];
      float ls = 0.f;
#pragma unroll
      for (int t = 0; t < 2; ++t) {
        f32x8 pe;
#pragma unroll
        for (int half = 0; half < 2; ++half)
#pragma unroll
          for (int r = 0; r < 4; ++r)
            pe[half * 4 + r] = EXP2(sv[2 * t + half][r]);
        float s0 = pe[0] + pe[1], s1 = pe[2] + pe[3];
        float s2 = pe[4] + pe[5], s3 = pe[6] + pe[7];
        ls += (s0 + s1) + (s2 + s3);
        pb[t] = __builtin_convertvector(pe, bf16x8);
      }
      lsv[sub] += ls;
#pragma unroll
      for (int dt = 0; dt < 4; ++dt) {
        oacc[sub][dt] = MFMA16(vf[dt][0], pb[0], oacc[sub][dt]);
        oacc[sub][dt] = MFMA16(vf[dt][1], pb[1], oacc[sub][dt]);
      }
    }
  }

#pragma unroll
  for (int sub = 0; sub < 4; ++sub) {
    lsv[sub] += __shfl_xor(lsv[sub], 16);
    lsv[sub] += __shfl_xor(lsv[sub], 32);
  }

  if (MODE == 0) {
    int b = bh >> 3, hh = bh & 7;
#pragma unroll
    for (int sub = 0; sub < 4; ++sub) {
      float inv = 1.f / lsv[sub];
      int qrow = qrow0 + sub * 16 + col;
      bf16_t* ob = po + ((size_t)b * NPIX + qrow) * CDIM + hh * 64 + quad * 4;
#pragma unroll
      for (int dt = 0; dt < 4; ++dt) {
        union {
          ushort4 u;
          bf16_t hv[4];
        } pk;
#pragma unroll
        for (int r = 0; r < 4; ++r)
          pk.hv[r] = (bf16_t)(oacc[sub][dt][r] * inv);
        *(ushort4*)(ob + dt * 16) = pk.u;
      }
    }
  } else {
    bf16_t* pbase = po + (size_t)kh * posz;
#pragma unroll
    for (int sub = 0; sub < 4; ++sub) {
      int qrow = qrow0 + sub * 16 + col;
      bf16_t* op = pbase + ((size_t)bh * NPIX + qrow) * 64 + quad * 4;
#pragma unroll
      for (int dt = 0; dt < 4; ++dt) {
        union {
          ushort4 u;
          bf16_t hv[4];
        } pk;
#pragma unroll
        for (int r = 0; r < 4; ++r) pk.hv[r] = (bf16_t)oacc[sub][dt][r];
        *(ushort4*)(op + dt * 16) = pk.u;
      }
    }
    if (quad == 0) {
      float* lbase = lsum + (size_t)(kh * 16 + bh) * NPIX;
#pragma unroll
      for (int sub = 0; sub < 4; ++sub)
        lbase[qrow0 + sub * 16 + col] = lsv[sub];
    }
  }
}

// ---------------------------------------------------------------------------
extern "C" void kernel_launch(void* const* d_in, const int* in_sizes, int n_in,
                              void* d_out, int out_size, void* d_ws,
                              size_t ws_size, hipStream_t stream) {
  const void* x = d_in[0];
  const void* dww = d_in[1];
  const void* qkvw = d_in[2];
  const void* projw = d_in[3];
  const void* projb = d_in[4];

  bf16_t* ws = (bf16_t*)d_ws;
  const size_t SZ = (size_t)2 * NPIX * CDIM;  // 4,194,304 elems per buffer
  bf16_t* yt = ws;           // y_t (B,N,C); dead after gemm1
  bf16_t* qa = ws + SZ;      // q (b,h,n,d), pre-scaled by QSCALE
  bf16_t* ka = ws + 2 * SZ;  // k (b,h,n,d)
  bf16_t* va = ws + 3 * SZ;  // vT (b,h,d,n), plain layout

  // Layout: O1 overlays yt (partial kh=0), O2 at ws+4SZ (partial stride
  // 4SZ), lsum (2*16*NPIX f32 = 262144 bf16-slots) at ws+5SZ, converted
  // weights wq/wp after lsum (1.05M elems, still < ws+6SZ), combined O at
  // ws+6SZ.
  const size_t needC = 7 * SZ * sizeof(bf16_t);
  const size_t need2 =
      5 * SZ * sizeof(bf16_t) + 2 * 16 * (size_t)NPIX * sizeof(float);

  if (ws_size >= needC) {
    bf16_t* O1 = yt;  // partial kh=0 overlays yt
    bf16_t* O2 = ws + 4 * SZ;
    float* ls2 = (float*)(ws + 5 * SZ);
    bf16_t* wq = ws + 5 * SZ + 262144;  // 786432 elems
    bf16_t* wp = wq + 786432;           // 262144 elems
    bf16_t* oc = ws + 6 * SZ;  // combined, gemm-B layout (z, n, 512)
    // fused: blocks 0-1023 dwconv, 1024-1535 weight convert
    dwconv_kernel<<<1536, 256, 0, stream>>>(x, dww, yt, qkvw, projw, wq, wp);
    // m-tile fastest: consecutive blocks share the B-tile (L2 reuse)
    gemm_kernel<128><<<dim3(12, 32, 2), 256, 0, stream>>>(
        wq, yt, qa, ka, va, nullptr, 0, 0, nullptr, 1);
    attn_kernel<2><<<512, 256, 0, stream>>>(qa, ka, va, O1, 4 * SZ, ls2);
    combine_kernel<<<2048, 256, 0, stream>>>(O1, O2, ls2, oc);
    // gemm2: BN=64 -> grid 512 = 2 blocks/CU (R12 experiment)
    gemm_kernel<64><<<dim3(4, 64, 2), 256, 0, stream>>>(
        wp, oc, d_out, nullptr, nullptr, projb, 1, 0, nullptr, 1);
  } else if (ws_size >= need2) {
    bf16_t* O1 = yt;  // partial s=0 overlays yt
    float* ls2 = (float*)(ws + 5 * SZ);
    dwconv_kernel<<<1024, 256, 0, stream>>>(x, dww, yt, nullptr, nullptr,
                                            nullptr, nullptr);
    gemm_kernel<128><<<dim3(12, 32, 2), 256, 0, stream>>>(
        qkvw, yt, qa, ka, va, nullptr, 0, 0, nullptr, 0);
    attn_kernel<2><<<512, 256, 0, stream>>>(qa, ka, va, O1, 4 * SZ, ls2);
    gemm_kernel<128><<<dim3(4, 32, 2), 256, 0, stream>>>(
        projw, O1, d_out, nullptr, nullptr, projb, 2, 4 * SZ, ls2, 0);
  } else {
    dwconv_kernel<<<1024, 256, 0, stream>>>(x, dww, yt, nullptr, nullptr,
                                            nullptr, nullptr);
    gemm_kernel<128><<<dim3(12, 32, 2), 256, 0, stream>>>(
        qkvw, yt, qa, ka, va, nullptr, 0, 0, nullptr, 0);
    attn_kernel<0><<<256, 256, 0, stream>>>(qa, ka, va, yt, 0, nullptr);
    gemm_kernel<128><<<dim3(4, 32, 2), 256, 0, stream>>>(
        projw, yt, d_out, nullptr, nullptr, projb, 1, 0, nullptr, 0);
  }
}